// Round 10
// baseline (623.566 us; speedup 1.0000x reference)
//
#include <hip/hip_runtime.h>
#include <stdint.h>

#define N_TOK 4096
#define DIM   2048
#define NH    16
#define HD    128
#define NW    (DIM * DIM)

using bf16x8 = __attribute__((ext_vector_type(8))) short;
using bf16x4 = __attribute__((ext_vector_type(4))) short;
using f32x4  = __attribute__((ext_vector_type(4))) float;
using u32x2  = __attribute__((ext_vector_type(2))) unsigned int;

#if __has_builtin(__builtin_amdgcn_exp2f)
#define EXP2(x) __builtin_amdgcn_exp2f(x)
#else
#define EXP2(x) exp2f(x)
#endif

__device__ inline unsigned short f2bf(float f) {
  union { float f; unsigned u; } v; v.f = f;
  unsigned r = v.u + 0x7FFFu + ((v.u >> 16) & 1u);
  return (unsigned short)(r >> 16);
}
__device__ inline float bf2f(unsigned short u) {
  union { unsigned u; float f; } v; v.u = ((unsigned)u) << 16; return v.f;
}
__device__ inline f32x4 mfma16(bf16x8 a, bf16x8 b, f32x4 c) {
  return __builtin_amdgcn_mfma_f32_16x16x32_bf16(a, b, c, 0, 0, 0);
}
// async global->LDS, 16B per lane; LDS dest = wave-uniform base + lane*16
__device__ inline void gll16(const unsigned short* g, unsigned short* l) {
  __builtin_amdgcn_global_load_lds(
      (const __attribute__((address_space(1))) void*)g,
      (__attribute__((address_space(3))) void*)l, 16, 0, 0);
}
// raw barrier with compiler-only memory fences (no waitcnt emitted)
__device__ inline void wgbar() {
  asm volatile("" ::: "memory");
  __builtin_amdgcn_s_barrier();
  asm volatile("" ::: "memory");
}

// pack two f32 -> one u32 of 2x bf16 (RNE). No builtin on gfx950 (guide T12).
__device__ inline unsigned cvtpk_bf16(float lo, float hi) {
  unsigned r;
  asm("v_cvt_pk_bf16_f32 %0, %1, %2" : "=v"(r) : "v"(lo), "v"(hi));
  return r;
}

// permlane swaps (gfx950). ret.x = {A.lo16/32-groups..}, see call sites.
__device__ inline u32x2 pl32swap(unsigned a, unsigned b) {
#if __has_builtin(__builtin_amdgcn_permlane32_swap)
  return __builtin_amdgcn_permlane32_swap(a, b, false, false);
#else
  int lane = threadIdx.x & 63;
  unsigned as = (unsigned)__shfl_xor((int)a, 32);
  unsigned bs = (unsigned)__shfl_xor((int)b, 32);
  u32x2 r;
  r.x = (lane & 32) ? bs : a;   // {A.lo32, B.lo32}
  r.y = (lane & 32) ? b : as;   // {A.hi32, B.hi32}
  return r;
#endif
}
__device__ inline u32x2 pl16swap(unsigned a, unsigned b) {
#if __has_builtin(__builtin_amdgcn_permlane16_swap)
  return __builtin_amdgcn_permlane16_swap(a, b, false, false);
#else
  int lane = threadIdx.x & 63;
  unsigned as = (unsigned)__shfl_xor((int)a, 16);
  unsigned bs = (unsigned)__shfl_xor((int)b, 16);
  u32x2 r;
  r.x = (lane & 16) ? bs : a;   // {A.g0, B.g0, A.g2, B.g2} (16-lane groups)
  r.y = (lane & 16) ? b : as;   // {A.g1, B.g1, A.g3, B.g3}
  return r;
#endif
}

// fp32 -> bf16 convert, 8 elems/thread
__global__ __launch_bounds__(256)
void cvt_bf16(const float* __restrict__ src, unsigned short* __restrict__ dst, int n) {
  int i = blockIdx.x * 256 + threadIdx.x;
  if (i * 8 >= n) return;
  const float4* s = (const float4*)src + (size_t)i * 2;
  float4 a = s[0], b = s[1];
  bf16x8 o;
  o[0] = (short)f2bf(a.x); o[1] = (short)f2bf(a.y);
  o[2] = (short)f2bf(a.z); o[3] = (short)f2bf(a.w);
  o[4] = (short)f2bf(b.x); o[5] = (short)f2bf(b.y);
  o[6] = (short)f2bf(b.z); o[7] = (short)f2bf(b.w);
  *(bf16x8*)(dst + (size_t)i * 8) = o;
}

// C[4096,2048] = A[4096,2048] @ B[2048,2048]^T (+bias)*scale; all-bf16 inputs.
// R8 structure (measured best): 2 coarse phases/K-tile, 16 MFMA per phase
// (m196 granularity sweet spot — R9's 8-MFMA phases regressed 24%).
// 3-deep LDS pipeline (144 KB), s_waitcnt vmcnt(6) once per K-tile (6 loads
// of tile t+2 stay in flight across barriers), MFMA under setprio.
// T1 chunked XCD swizzle: nb=(bid&7)*32+(bid>>3), m-major -> each XCD = 2
// m-rows x 16 n-blocks, shared A = 2 MB (L2-fits). T2 swizzle via
// pre-swizzled GLOBAL source col (rule 21) + XOR'd ds_read slot.
// Hazards: stage(t+2) writes buf[(t+2)%3]=buf[(t-1)%3], last read >=2
// barriers upstream; vmcnt(6)+barrier orders tile t+1 loads before any wave
// reads them. Epilogue peels last 2 tiles (vmcnt(0)).
// OUT_MODE: 0 = bf16 row-major, 1 = fp32 row-major, 2 = bf16 transposed (Vt)
template<int OUT_MODE>
__global__ __launch_bounds__(512, 2)
void gemm_bf16(const unsigned short* __restrict__ A, const unsigned short* __restrict__ B,
               const float* __restrict__ bias, void* __restrict__ out_, float scale) {
  constexpr int BM = 256, BN = 128, BK = 64;
  constexpr int NKT = DIM / BK;              // 32
  __shared__ unsigned short Asl[3][BM * BK]; // 3 x 32 KB
  __shared__ unsigned short Bsl[3][BN * BK]; // 3 x 16 KB  (total 144 KB)

  const int tid  = threadIdx.x;
  const int lane = tid & 63;
  const int w    = tid >> 6;
  const int wm = w >> 1, wn = w & 1;         // 4M x 2N
  const int lr = lane & 15, quad = lane >> 4;

  // T1 chunked XCD swizzle: contiguous 32-block chunk per XCD, m-major.
  const int bid = blockIdx.x;                // 0..255
  const int nb  = (bid & 7) * 32 + (bid >> 3);
  const int m0  = (nb >> 4) * BM;            // 16 m-blocks
  const int n0  = (nb & 15) * BN;            // 16 n-blocks

  const f32x4 vzero = {0.f, 0.f, 0.f, 0.f};
  f32x4 acc[4][4];
#pragma unroll
  for (int i = 0; i < 4; ++i)
#pragma unroll
    for (int j = 0; j < 4; ++j) acc[i][j] = vzero;

  // staging descriptors: A = 4 chunks/thread, B = 2 chunks/thread (16B each).
  // LDS write linear at ch*16B; global source col pre-swizzled (m173).
  size_t asrc[4]; int aldst[4];
  size_t bsrc[2]; int bldst[2];
#pragma unroll
  for (int i = 0; i < 4; ++i) {
    int ch = tid + i * 512;                  // 0..2047
    int row = ch >> 3, cc = ch & 7;
    int gcc = cc ^ (row & 7);
    asrc[i]  = (size_t)(m0 + row) * DIM + gcc * 8;
    aldst[i] = ch * 8;
  }
#pragma unroll
  for (int i = 0; i < 2; ++i) {
    int ch = tid + i * 512;                  // 0..1023
    int row = ch >> 3, cc = ch & 7;
    int gcc = cc ^ (row & 7);
    bsrc[i]  = (size_t)(n0 + row) * DIM + gcc * 8;
    bldst[i] = ch * 8;
  }
  // half 0: A0, A1, B0 ; half 1: A2, A3, B1  (3 gll16 each)
  auto stage_half = [&](int buf, int k0, int half) {
    int a0 = half * 2;
    gll16(&A[asrc[a0] + k0],     &Asl[buf][aldst[a0]]);
    gll16(&A[asrc[a0 + 1] + k0], &Asl[buf][aldst[a0 + 1]]);
    gll16(&B[bsrc[half] + k0],   &Bsl[buf][bldst[half]]);
  };

  auto lda = [&](int buf, int ks, bf16x8* af) {
#pragma unroll
    for (int mb = 0; mb < 4; ++mb) {
      int row  = wm * 64 + mb * 16 + lr;
      int slot = (ks * 4 + quad) ^ (row & 7);
      af[mb] = *(const bf16x8*)&Asl[buf][row * 64 + slot * 8];
    }
  };
  auto ldb = [&](int buf, int ks, bf16x8* bfv) {
#pragma unroll
    for (int nb2 = 0; nb2 < 4; ++nb2) {
      int row  = wn * 64 + nb2 * 16 + lr;
      int slot = (ks * 4 + quad) ^ (row & 7);
      bfv[nb2] = *(const bf16x8*)&Bsl[buf][row * 64 + slot * 8];
    }
  };
  auto mm = [&](bf16x8* af, bf16x8* bfv) {
    __builtin_amdgcn_s_setprio(1);
#pragma unroll
    for (int mb = 0; mb < 4; ++mb)
#pragma unroll
      for (int nb2 = 0; nb2 < 4; ++nb2)
        acc[mb][nb2] = mfma16(af[mb], bfv[nb2], acc[mb][nb2]);
    __builtin_amdgcn_s_setprio(0);
  };

  // ---- prologue: stage tiles 0 and 1; wait tile 0 (6 in flight stays) ----
  stage_half(0, 0, 0);  stage_half(0, 0, 1);
  stage_half(1, BK, 0); stage_half(1, BK, 1);
  asm volatile("s_waitcnt vmcnt(6)" ::: "memory");
  wgbar();

  // ---- main loop: tiles 0..NKT-3, staging t+2, vmcnt(6) per K-tile ----
  for (int t = 0; t < NKT - 2; ++t) {
    const int buf = t % 3, sb = (t + 2) % 3, sk = (t + 2) * BK;
    bf16x8 af[4], bfv[4];
    // phase 0 (k-slice 0)
    lda(buf, 0, af); ldb(buf, 0, bfv);
    stage_half(sb, sk, 0);
    wgbar();
    mm(af, bfv);
    wgbar();
    // phase 1 (k-slice 1)
    lda(buf, 1, af); ldb(buf, 1, bfv);
    stage_half(sb, sk, 1);
    asm volatile("s_waitcnt vmcnt(6)" ::: "memory");  // tile t+1 landed
    wgbar();
    mm(af, bfv);
    wgbar();
  }
  // ---- epilogue tile NKT-2: no staging; drain tile NKT-1 ----
  {
    const int buf = (NKT - 2) % 3;
    bf16x8 af[4], bfv[4];
    lda(buf, 0, af); ldb(buf, 0, bfv);
    wgbar(); mm(af, bfv); wgbar();
    lda(buf, 1, af); ldb(buf, 1, bfv);
    asm volatile("s_waitcnt vmcnt(0)" ::: "memory");  // tile NKT-1 landed
    wgbar(); mm(af, bfv); wgbar();
  }
  // ---- epilogue tile NKT-1: pure compute ----
  {
    const int buf = (NKT - 1) % 3;
    bf16x8 af[4], bfv[4];
    lda(buf, 0, af); ldb(buf, 0, bfv);
    mm(af, bfv);
    lda(buf, 1, af); ldb(buf, 1, bfv);
    mm(af, bfv);
  }

  // ---- C write ----
#pragma unroll
  for (int mb = 0; mb < 4; ++mb)
#pragma unroll
    for (int nb2 = 0; nb2 < 4; ++nb2) {
      int gn = n0 + wn * 64 + nb2 * 16 + lr;
      int gm_base = m0 + wm * 64 + mb * 16 + quad * 4;
      float bs = bias[gn];
      if constexpr (OUT_MODE == 2) {
        bf16x4 pk;
#pragma unroll
        for (int r = 0; r < 4; ++r) pk[r] = (short)f2bf((acc[mb][nb2][r] + bs) * scale);
        *(bf16x4*)&((unsigned short*)out_)[(size_t)gn * N_TOK + gm_base] = pk;
      } else {
#pragma unroll
        for (int r = 0; r < 4; ++r) {
          float v = (acc[mb][nb2][r] + bs) * scale;
          if constexpr (OUT_MODE == 1)
            ((float*)out_)[(size_t)(gm_base + r) * DIM + gn] = v;
          else
            ((unsigned short*)out_)[(size_t)(gm_base + r) * DIM + gn] = f2bf(v);
        }
      }
    }
}

// Flash attention, no-max softmax (scores bounded; exp2 domain folded into Q).
// R10: KVBLK 64 -> 128. Attn is serial-chain/sync bound at 1 wave/SIMD (R8
// proved not memory-bound: FETCH 139->24.7 MB, dur unchanged). Halving the
// iteration count (64->32) halves barriers, prefetch-issue events, and
// pipeline fill/drain, doubling the MFMA run length between syncs (256/iter).
// Softmax permlane mapping generalizes: nf = 2ki + (q>>1), ki<4 (re-derived).
// LDS 2x68 KB = 136 KB (1 block/CU; grid-capped anyway).
// Head-chunked XCD swizzle (R8): XCD x owns heads {2x,2x+1}; each XCD's 32
// blocks share 2 heads' K+V = 4 MB = its L2.
// mb=4 (64 q-rows/wave); swapped QK^T (mfma(K,Q)) -> in-register softmax.
__global__ __launch_bounds__(256, 1)
void flash_attn(const unsigned short* __restrict__ Q,
                const unsigned short* __restrict__ K,
                const unsigned short* __restrict__ Vt,
                unsigned short* __restrict__ ctx) {
  constexpr int KVB = 128;
  constexpr int LDK = 136;  // K tile row stride (128 d + 8 pad)
  constexpr int LDV = 136;  // Vt tile row stride (128 keys + 8 pad)
  constexpr int NT  = N_TOK / KVB;  // 32
  __shared__ unsigned short Ksl[KVB * LDK];   // 128 keys x 128 d
  __shared__ unsigned short VTsl[128 * LDV];  // 128 d x 128 keys

  const int tid  = threadIdx.x;
  const int lane = tid & 63, w = tid >> 6;
  const int lr = lane & 15, quad = lane >> 4;

  // head-chunked XCD swizzle (bijective: bid = qb*16 + b1*8 + x)
  const int bid  = blockIdx.x;                   // 0..255
  const int head = (bid & 7) * 2 + ((bid >> 3) & 1);
  const int qblk = bid >> 4;
  const int hoff = head * HD;
  const int q0   = qblk * 256;
  const int qw   = q0 + w * 64;

  // Q fragments; L2E/sqrt(128) already folded in at projection.
  // Layout [free=lr (q-row)][k=c*32+quad*8] = B-operand of swapped mfma(K,Q).
  bf16x8 qf[4][4];
#pragma unroll
  for (int mb = 0; mb < 4; ++mb)
#pragma unroll
    for (int c = 0; c < 4; ++c)
      qf[mb][c] = *(const bf16x8*)&Q[(size_t)(qw + mb * 16 + lr) * DIM + hoff + c * 32 + quad * 8];

  const f32x4 vzero = {0.f, 0.f, 0.f, 0.f};
  f32x4 o[4][8];
  float l_acc[4] = {0.f, 0.f, 0.f, 0.f};  // row-sum for q-row = lr (per mb)
#pragma unroll
  for (int mb = 0; mb < 4; ++mb)
#pragma unroll
    for (int nb = 0; nb < 8; ++nb) o[mb][nb] = vzero;

  // 128-key tile = 2048 16B chunks; 256 threads x 8 chunks each (K and V)
  bf16x8 kreg[8], vreg[8];
  auto load_tile = [&](int kt) {
    int kbase = kt * KVB;
#pragma unroll
    for (int i = 0; i < 8; ++i) {
      int ch = tid + i * 256;
      kreg[i] = *(const bf16x8*)&K[(size_t)(kbase + (ch >> 4)) * DIM + hoff + (ch & 15) * 8];
      vreg[i] = *(const bf16x8*)&Vt[(size_t)(hoff + (ch >> 4)) * N_TOK + kbase + (ch & 15) * 8];
    }
  };
  load_tile(0);

  for (int kt = 0; kt < NT; ++kt) {
    __syncthreads();  // previous tile's LDS reads complete
#pragma unroll
    for (int i = 0; i < 8; ++i) {
      int ch = tid + i * 256;
      *(bf16x8*)&Ksl[(ch >> 4) * LDK + (ch & 15) * 8] = kreg[i];
      *(bf16x8*)&VTsl[(ch >> 4) * LDV + (ch & 15) * 8] = vreg[i];
    }
    __syncthreads();
    if (kt + 1 < NT) load_tile(kt + 1);  // global->reg prefetch under compute

    // S^T = K @ Q^T : lane holds S[q = mb*16+lr][key = nf*16 + quad*4 + r]
    f32x4 s[4][8];
#pragma unroll
    for (int mb = 0; mb < 4; ++mb)
#pragma unroll
      for (int nf = 0; nf < 8; ++nf) s[mb][nf] = vzero;
#pragma unroll
    for (int nf = 0; nf < 8; ++nf)
#pragma unroll
      for (int c = 0; c < 4; ++c) {
        bf16x8 kf = *(const bf16x8*)&Ksl[(nf * 16 + lr) * LDK + c * 32 + quad * 8];
#pragma unroll
        for (int mb = 0; mb < 4; ++mb) s[mb][nf] = mfma16(kf, qf[mb][c], s[mb][nf]);
      }

    // In-register softmax + redistribution into PV A-fragments.
    // Target word t of pf[mb][ki] (lane quad q) = keys ki*32 + q*8 + {2t,2t+1}
    //   = source lane quad (q&1)*2 + (t>>1), W[2ki + (q>>1)][t&1]  (ki 0..3).
    bf16x8 pf[4][4];
#pragma unroll
    for (int mb = 0; mb < 4; ++mb) {
      unsigned W[8][2];
      float lp = 0.f;
#pragma unroll
      for (int nf = 0; nf < 8; ++nf) {
        float e0 = EXP2(s[mb][nf][0]);
        float e1 = EXP2(s[mb][nf][1]);
        float e2 = EXP2(s[mb][nf][2]);
        float e3 = EXP2(s[mb][nf][3]);
        lp += (e0 + e1) + (e2 + e3);
        W[nf][0] = cvtpk_bf16(e0, e1);
        W[nf][1] = cvtpk_bf16(e2, e3);
      }
      l_acc[mb] += lp;
#pragma unroll
      for (int ki = 0; ki < 4; ++ki) {
        u32x2 a0  = pl32swap(W[2 * ki][0], W[2 * ki + 1][0]);
        u32x2 t02 = pl16swap(a0.x, a0.y);   // (T0, T2)
        u32x2 a1  = pl32swap(W[2 * ki][1], W[2 * ki + 1][1]);
        u32x2 t13 = pl16swap(a1.x, a1.y);   // (T1, T3)
        union { unsigned u[4]; bf16x8 v; } pu;
        pu.u[0] = t02.x; pu.u[1] = t13.x; pu.u[2] = t02.y; pu.u[3] = t13.y;
        pf[mb][ki] = pu.v;
      }
    }

    // O += P @ V  (kf/vf reuse across 4 mb is the LDS-traffic win)
#pragma unroll
    for (int nb = 0; nb < 8; ++nb)
#pragma unroll
      for (int ki = 0; ki < 4; ++ki) {
        bf16x8 vf = *(const bf16x8*)&VTsl[(nb * 16 + lr) * LDV + ki * 32 + quad * 8];
#pragma unroll
        for (int mb = 0; mb < 4; ++mb) o[mb][nb] = mfma16(pf[mb][ki], vf, o[mb][nb]);
      }
  }

  // Row-sums live at q-row = lr; reduce the 4 quad-slices, then transpose
  // to q = quad*4+r via shfl for the store.
#pragma unroll
  for (int mb = 0; mb < 4; ++mb) {
    float t = l_acc[mb];
    t += __shfl_xor(t, 16);
    t += __shfl_xor(t, 32);
    l_acc[mb] = t;  // all lanes: L[mb][lr]
  }
#pragma unroll
  for (int mb = 0; mb < 4; ++mb)
#pragma unroll
    for (int r = 0; r < 4; ++r) {
      float Lr = __shfl(l_acc[mb], quad * 4 + r);  // L for q-row quad*4+r
      float inv = 1.0f / Lr;
      int gq = qw + mb * 16 + quad * 4 + r;
#pragma unroll
      for (int nb = 0; nb < 8; ++nb)
        ctx[(size_t)gq * DIM + hoff + nb * 16 + lr] = f2bf(o[mb][nb][r] * inv);
    }
}

extern "C" void kernel_launch(void* const* d_in, const int* in_sizes, int n_in,
                              void* d_out, int out_size, void* d_ws, size_t ws_size,
                              hipStream_t stream) {
  (void)in_sizes; (void)n_in; (void)out_size; (void)ws_size;
  const float* x  = (const float*)d_in[0];
  const float* Wq = (const float*)d_in[1];
  const float* bq = (const float*)d_in[2];
  const float* Wk = (const float*)d_in[3];
  const float* bk = (const float*)d_in[4];
  const float* Wv = (const float*)d_in[5];
  const float* bv = (const float*)d_in[6];
  const float* Wo = (const float*)d_in[7];
  const float* bo = (const float*)d_in[8];

  const size_t NE = (size_t)N_TOK * DIM;  // 8.4M
  unsigned short* xb  = (unsigned short*)d_ws;      // also reused as ctx later
  unsigned short* Wqb = xb + NE;
  unsigned short* Wkb = Wqb + NW;
  unsigned short* Wvb = Wkb + NW;
  unsigned short* Wob = Wvb + NW;
  unsigned short* Qb  = Wob + NW;
  unsigned short* Kb  = Qb + NE;
  unsigned short* Vtb = Kb + NE;   // total ~100.7 MB

  cvt_bf16<<<4096, 256, 0, stream>>>(x,  xb,  (int)NE);
  cvt_bf16<<<2048, 256, 0, stream>>>(Wq, Wqb, NW);
  cvt_bf16<<<2048, 256, 0, stream>>>(Wk, Wkb, NW);
  cvt_bf16<<<2048, 256, 0, stream>>>(Wv, Wvb, NW);
  cvt_bf16<<<2048, 256, 0, stream>>>(Wo, Wob, NW);

  // flat 256-block grids; XCD chunking + decomp inside the kernels (T1)
  const float qscale = 1.4426950408889634f * 0.08838834764831845f;

  gemm_bf16<0><<<256, 512, 0, stream>>>(xb, Wqb, bq, Qb, qscale);
  gemm_bf16<0><<<256, 512, 0, stream>>>(xb, Wkb, bk, Kb, 1.0f);
  gemm_bf16<2><<<256, 512, 0, stream>>>(xb, Wvb, bv, Vtb, 1.0f);

  unsigned short* ctxb = xb;  // x dead after V projection; reuse
  flash_attn<<<256, 256, 0, stream>>>(Qb, Kb, Vtb, ctxb);

  gemm_bf16<1><<<256, 512, 0, stream>>>(ctxb, Wob, bo, (float*)d_out, 1.0f);
}

// Round 11
// 453.379 us; speedup vs baseline: 1.3754x; 1.3754x over previous
//
#include <hip/hip_runtime.h>
#include <stdint.h>

#define N_TOK 4096
#define DIM   2048
#define NH    16
#define HD    128
#define NW    (DIM * DIM)

using bf16x8 = __attribute__((ext_vector_type(8))) short;
using bf16x4 = __attribute__((ext_vector_type(4))) short;
using f32x4  = __attribute__((ext_vector_type(4))) float;
using u32x2  = __attribute__((ext_vector_type(2))) unsigned int;

#if __has_builtin(__builtin_amdgcn_exp2f)
#define EXP2(x) __builtin_amdgcn_exp2f(x)
#else
#define EXP2(x) exp2f(x)
#endif

__device__ inline unsigned short f2bf(float f) {
  union { float f; unsigned u; } v; v.f = f;
  unsigned r = v.u + 0x7FFFu + ((v.u >> 16) & 1u);
  return (unsigned short)(r >> 16);
}
__device__ inline float bf2f(unsigned short u) {
  union { unsigned u; float f; } v; v.u = ((unsigned)u) << 16; return v.f;
}
__device__ inline f32x4 mfma16(bf16x8 a, bf16x8 b, f32x4 c) {
  return __builtin_amdgcn_mfma_f32_16x16x32_bf16(a, b, c, 0, 0, 0);
}
// async global->LDS, 16B per lane; LDS dest = wave-uniform base + lane*16
__device__ inline void gll16(const unsigned short* g, unsigned short* l) {
  __builtin_amdgcn_global_load_lds(
      (const __attribute__((address_space(1))) void*)g,
      (__attribute__((address_space(3))) void*)l, 16, 0, 0);
}
// raw barrier with compiler-only memory fences (no waitcnt emitted)
__device__ inline void wgbar() {
  asm volatile("" ::: "memory");
  __builtin_amdgcn_s_barrier();
  asm volatile("" ::: "memory");
}

// pack two f32 -> one u32 of 2x bf16 (RNE). No builtin on gfx950 (guide T12).
__device__ inline unsigned cvtpk_bf16(float lo, float hi) {
  unsigned r;
  asm("v_cvt_pk_bf16_f32 %0, %1, %2" : "=v"(r) : "v"(lo), "v"(hi));
  return r;
}

// permlane swaps (gfx950). ret.x = {A.lo16/32-groups..}, see call sites.
__device__ inline u32x2 pl32swap(unsigned a, unsigned b) {
#if __has_builtin(__builtin_amdgcn_permlane32_swap)
  return __builtin_amdgcn_permlane32_swap(a, b, false, false);
#else
  int lane = threadIdx.x & 63;
  unsigned as = (unsigned)__shfl_xor((int)a, 32);
  unsigned bs = (unsigned)__shfl_xor((int)b, 32);
  u32x2 r;
  r.x = (lane & 32) ? bs : a;   // {A.lo32, B.lo32}
  r.y = (lane & 32) ? b : as;   // {A.hi32, B.hi32}
  return r;
#endif
}
__device__ inline u32x2 pl16swap(unsigned a, unsigned b) {
#if __has_builtin(__builtin_amdgcn_permlane16_swap)
  return __builtin_amdgcn_permlane16_swap(a, b, false, false);
#else
  int lane = threadIdx.x & 63;
  unsigned as = (unsigned)__shfl_xor((int)a, 16);
  unsigned bs = (unsigned)__shfl_xor((int)b, 16);
  u32x2 r;
  r.x = (lane & 16) ? bs : a;   // {A.g0, B.g0, A.g2, B.g2} (16-lane groups)
  r.y = (lane & 16) ? b : as;   // {A.g1, B.g1, A.g3, B.g3}
  return r;
#endif
}

// fp32 -> bf16 convert, 8 elems/thread
__global__ __launch_bounds__(256)
void cvt_bf16(const float* __restrict__ src, unsigned short* __restrict__ dst, int n) {
  int i = blockIdx.x * 256 + threadIdx.x;
  if (i * 8 >= n) return;
  const float4* s = (const float4*)src + (size_t)i * 2;
  float4 a = s[0], b = s[1];
  bf16x8 o;
  o[0] = (short)f2bf(a.x); o[1] = (short)f2bf(a.y);
  o[2] = (short)f2bf(a.z); o[3] = (short)f2bf(a.w);
  o[4] = (short)f2bf(b.x); o[5] = (short)f2bf(b.y);
  o[6] = (short)f2bf(b.z); o[7] = (short)f2bf(b.w);
  *(bf16x8*)(dst + (size_t)i * 8) = o;
}

// C[4096,2048] = A[4096,2048] @ B[2048,2048]^T (+bias)*scale; all-bf16 inputs.
// R11: ONE barrier region per K-tile (32 MFMA between barriers). Barrier
// series: 8/K-tile (R9) = 505 us total; 4/K-tile (R8) = 436; this = 2/K-tile.
// Per K-tile: {ds_read ks0 | stage 6 gll16 -> wgbar -> 16 MFMA -> ds_read ks1
// (in-wave overlap with MFMAs) -> 16 MFMA -> vmcnt(6) -> wgbar}. vmcnt(6)
// after the MFMAs drains tile t+1 (issued a full K-tile earlier -> free wait).
// 3-deep LDS (144 KB). T1 chunked XCD swizzle: nb=(bid&7)*32+(bid>>3),
// m-major -> each XCD = 2 m-rows x 16 n-blocks, shared A = 2 MB (L2-fits).
// T2 swizzle via pre-swizzled GLOBAL source col (rule 21) + XOR'd ds_read slot.
// Hazards: stage(t+2) writes buf[(t+2)%3]=buf[(t-1)%3], last read >=2
// barriers upstream; vmcnt(6)+trailing barrier orders tile t+1 loads before
// its readers (next iter). Epilogue peels last 2 tiles (vmcnt(0)).
// OUT_MODE: 0 = bf16 row-major, 1 = fp32 row-major, 2 = bf16 transposed (Vt)
template<int OUT_MODE>
__global__ __launch_bounds__(512, 2)
void gemm_bf16(const unsigned short* __restrict__ A, const unsigned short* __restrict__ B,
               const float* __restrict__ bias, void* __restrict__ out_, float scale) {
  constexpr int BM = 256, BN = 128, BK = 64;
  constexpr int NKT = DIM / BK;              // 32
  __shared__ unsigned short Asl[3][BM * BK]; // 3 x 32 KB
  __shared__ unsigned short Bsl[3][BN * BK]; // 3 x 16 KB  (total 144 KB)

  const int tid  = threadIdx.x;
  const int lane = tid & 63;
  const int w    = tid >> 6;
  const int wm = w >> 1, wn = w & 1;         // 4M x 2N
  const int lr = lane & 15, quad = lane >> 4;

  // T1 chunked XCD swizzle: contiguous 32-block chunk per XCD, m-major.
  const int bid = blockIdx.x;                // 0..255
  const int nb  = (bid & 7) * 32 + (bid >> 3);
  const int m0  = (nb >> 4) * BM;            // 16 m-blocks
  const int n0  = (nb & 15) * BN;            // 16 n-blocks

  const f32x4 vzero = {0.f, 0.f, 0.f, 0.f};
  f32x4 acc[4][4];
#pragma unroll
  for (int i = 0; i < 4; ++i)
#pragma unroll
    for (int j = 0; j < 4; ++j) acc[i][j] = vzero;

  // staging descriptors: A = 4 chunks/thread, B = 2 chunks/thread (16B each).
  // LDS write linear at ch*16B; global source col pre-swizzled (m173).
  size_t asrc[4]; int aldst[4];
  size_t bsrc[2]; int bldst[2];
#pragma unroll
  for (int i = 0; i < 4; ++i) {
    int ch = tid + i * 512;                  // 0..2047
    int row = ch >> 3, cc = ch & 7;
    int gcc = cc ^ (row & 7);
    asrc[i]  = (size_t)(m0 + row) * DIM + gcc * 8;
    aldst[i] = ch * 8;
  }
#pragma unroll
  for (int i = 0; i < 2; ++i) {
    int ch = tid + i * 512;                  // 0..1023
    int row = ch >> 3, cc = ch & 7;
    int gcc = cc ^ (row & 7);
    bsrc[i]  = (size_t)(n0 + row) * DIM + gcc * 8;
    bldst[i] = ch * 8;
  }
  auto stage_all = [&](int buf, int k0) {    // 6 gll16: whole tile t+2
    gll16(&A[asrc[0] + k0], &Asl[buf][aldst[0]]);
    gll16(&A[asrc[1] + k0], &Asl[buf][aldst[1]]);
    gll16(&A[asrc[2] + k0], &Asl[buf][aldst[2]]);
    gll16(&A[asrc[3] + k0], &Asl[buf][aldst[3]]);
    gll16(&B[bsrc[0] + k0], &Bsl[buf][bldst[0]]);
    gll16(&B[bsrc[1] + k0], &Bsl[buf][bldst[1]]);
  };

  auto lda = [&](int buf, int ks, bf16x8* af) {
#pragma unroll
    for (int mb = 0; mb < 4; ++mb) {
      int row  = wm * 64 + mb * 16 + lr;
      int slot = (ks * 4 + quad) ^ (row & 7);
      af[mb] = *(const bf16x8*)&Asl[buf][row * 64 + slot * 8];
    }
  };
  auto ldb = [&](int buf, int ks, bf16x8* bfv) {
#pragma unroll
    for (int nb2 = 0; nb2 < 4; ++nb2) {
      int row  = wn * 64 + nb2 * 16 + lr;
      int slot = (ks * 4 + quad) ^ (row & 7);
      bfv[nb2] = *(const bf16x8*)&Bsl[buf][row * 64 + slot * 8];
    }
  };
  auto mm = [&](bf16x8* af, bf16x8* bfv) {   // 16 MFMA
    __builtin_amdgcn_s_setprio(1);
#pragma unroll
    for (int mb = 0; mb < 4; ++mb)
#pragma unroll
      for (int nb2 = 0; nb2 < 4; ++nb2)
        acc[mb][nb2] = mfma16(af[mb], bfv[nb2], acc[mb][nb2]);
    __builtin_amdgcn_s_setprio(0);
  };

  // ---- prologue: stage tiles 0 and 1; wait tile 0 (tile 1 stays in flight) ----
  stage_all(0, 0);
  stage_all(1, BK);
  asm volatile("s_waitcnt vmcnt(6)" ::: "memory");
  wgbar();

  // ---- main loop: one barrier region per K-tile, 32 MFMA inside ----
  for (int t = 0; t < NKT - 2; ++t) {
    const int buf = t % 3, sb = (t + 2) % 3, sk = (t + 2) * BK;
    bf16x8 af[4], bfv[4];
    lda(buf, 0, af); ldb(buf, 0, bfv);       // ks0 frags
    stage_all(sb, sk);                       // tile t+2 async
    wgbar();
    mm(af, bfv);                             // 16 MFMA (ks0)
    lda(buf, 1, af); ldb(buf, 1, bfv);       // ks1 frags overlap MFMAs
    mm(af, bfv);                             // 16 MFMA (ks1)
    asm volatile("s_waitcnt vmcnt(6)" ::: "memory");  // tile t+1 landed (free)
    wgbar();
  }
  // ---- epilogue tile NKT-2: no staging; drain tile NKT-1 ----
  {
    const int buf = (NKT - 2) % 3;
    bf16x8 af[4], bfv[4];
    lda(buf, 0, af); ldb(buf, 0, bfv);
    wgbar();
    mm(af, bfv);
    lda(buf, 1, af); ldb(buf, 1, bfv);
    mm(af, bfv);
    asm volatile("s_waitcnt vmcnt(0)" ::: "memory");  // tile NKT-1 landed
    wgbar();
  }
  // ---- epilogue tile NKT-1: pure compute ----
  {
    const int buf = (NKT - 1) % 3;
    bf16x8 af[4], bfv[4];
    lda(buf, 0, af); ldb(buf, 0, bfv);
    mm(af, bfv);
    lda(buf, 1, af); ldb(buf, 1, bfv);
    mm(af, bfv);
  }

  // ---- C write ----
#pragma unroll
  for (int mb = 0; mb < 4; ++mb)
#pragma unroll
    for (int nb2 = 0; nb2 < 4; ++nb2) {
      int gn = n0 + wn * 64 + nb2 * 16 + lr;
      int gm_base = m0 + wm * 64 + mb * 16 + quad * 4;
      float bs = bias[gn];
      if constexpr (OUT_MODE == 2) {
        bf16x4 pk;
#pragma unroll
        for (int r = 0; r < 4; ++r) pk[r] = (short)f2bf((acc[mb][nb2][r] + bs) * scale);
        *(bf16x4*)&((unsigned short*)out_)[(size_t)gn * N_TOK + gm_base] = pk;
      } else {
#pragma unroll
        for (int r = 0; r < 4; ++r) {
          float v = (acc[mb][nb2][r] + bs) * scale;
          if constexpr (OUT_MODE == 1)
            ((float*)out_)[(size_t)(gm_base + r) * DIM + gn] = v;
          else
            ((unsigned short*)out_)[(size_t)(gm_base + r) * DIM + gn] = f2bf(v);
        }
      }
    }
}

// Flash attention, no-max softmax (scores bounded; exp2 domain folded into Q).
// R8 structure EXACTLY (measured best, 162.5 us): KVBLK=64, mb=4 (64 q-rows/
// wave), grid 256 = 1 block/CU. R10's KVB=128 spilled (VGPR>256, scratch
// writes 38 MB, 341 us) — attn occupancy is structurally capped at 1 wave/
// SIMD (1024 waves total) and its register budget is saturated; frozen here.
// Head-chunked XCD swizzle: XCD x owns heads {2x,2x+1}; each XCD's 32 blocks
// share 2 heads' K+V = 4 MB = its L2 (measured: FETCH 139 -> 24.7 MB).
// Swapped QK^T (mfma(K,Q)) -> softmax fully in registers (cvt_pk + permlane).
__global__ __launch_bounds__(256, 1)
void flash_attn(const unsigned short* __restrict__ Q,
                const unsigned short* __restrict__ K,
                const unsigned short* __restrict__ Vt,
                unsigned short* __restrict__ ctx) {
  constexpr int LDK = 136;  // K tile row stride (128+8)
  constexpr int LDV = 72;   // Vt tile row stride (64+8)
  constexpr int NT  = N_TOK / 64;
  __shared__ unsigned short Ksl[64 * LDK];
  __shared__ unsigned short VTsl[128 * LDV];

  const int tid  = threadIdx.x;
  const int lane = tid & 63, w = tid >> 6;
  const int lr = lane & 15, quad = lane >> 4;

  // head-chunked XCD swizzle (bijective: bid = qb*16 + b1*8 + x)
  const int bid  = blockIdx.x;                   // 0..255
  const int head = (bid & 7) * 2 + ((bid >> 3) & 1);
  const int qblk = bid >> 4;
  const int hoff = head * HD;
  const int q0   = qblk * 256;
  const int qw   = q0 + w * 64;

  // Q fragments; L2E/sqrt(128) already folded in at projection.
  // Layout [free=lr (q-row)][k=c*32+quad*8] = B-operand of swapped mfma(K,Q).
  bf16x8 qf[4][4];
#pragma unroll
  for (int mb = 0; mb < 4; ++mb)
#pragma unroll
    for (int c = 0; c < 4; ++c)
      qf[mb][c] = *(const bf16x8*)&Q[(size_t)(qw + mb * 16 + lr) * DIM + hoff + c * 32 + quad * 8];

  const f32x4 vzero = {0.f, 0.f, 0.f, 0.f};
  f32x4 o[4][8];
  float l_acc[4] = {0.f, 0.f, 0.f, 0.f};  // row-sum for q-row = lr (per mb)
#pragma unroll
  for (int mb = 0; mb < 4; ++mb)
#pragma unroll
    for (int nb = 0; nb < 8; ++nb) o[mb][nb] = vzero;

  bf16x8 kreg[4], vreg[4];
  auto load_tile = [&](int kt) {
    int kbase = kt * 64;
#pragma unroll
    for (int i = 0; i < 4; ++i) {
      int ch = tid + i * 256;
      kreg[i] = *(const bf16x8*)&K[(size_t)(kbase + (ch >> 4)) * DIM + hoff + (ch & 15) * 8];
      vreg[i] = *(const bf16x8*)&Vt[(size_t)(hoff + (ch >> 3)) * N_TOK + kbase + (ch & 7) * 8];
    }
  };
  load_tile(0);

  for (int kt = 0; kt < NT; ++kt) {
    __syncthreads();  // previous tile's LDS reads complete
#pragma unroll
    for (int i = 0; i < 4; ++i) {
      int ch = tid + i * 256;
      *(bf16x8*)&Ksl[(ch >> 4) * LDK + (ch & 15) * 8] = kreg[i];
      *(bf16x8*)&VTsl[(ch >> 3) * LDV + (ch & 7) * 8] = vreg[i];
    }
    __syncthreads();
    if (kt + 1 < NT) load_tile(kt + 1);  // global->reg prefetch under compute

    // S^T = K @ Q^T : lane holds S[q = mb*16+lr][key = nf*16 + quad*4 + r]
    f32x4 s[4][4];
#pragma unroll
    for (int mb = 0; mb < 4; ++mb)
#pragma unroll
      for (int nf = 0; nf < 4; ++nf) s[mb][nf] = vzero;
#pragma unroll
    for (int nf = 0; nf < 4; ++nf)
#pragma unroll
      for (int c = 0; c < 4; ++c) {
        bf16x8 kf = *(const bf16x8*)&Ksl[(nf * 16 + lr) * LDK + c * 32 + quad * 8];
#pragma unroll
        for (int mb = 0; mb < 4; ++mb) s[mb][nf] = mfma16(kf, qf[mb][c], s[mb][nf]);
      }

    // In-register softmax + redistribution into PV A-fragments.
    // Target word t of pf[mb][ki] (lane quad q) = keys ki*32 + q*8 + {2t,2t+1}
    //   = source lane quad (q&1)*2 + (t>>1), W[2ki + (q>>1)][t&1].
    bf16x8 pf[4][2];
#pragma unroll
    for (int mb = 0; mb < 4; ++mb) {
      unsigned W[4][2];
      float lp = 0.f;
#pragma unroll
      for (int nf = 0; nf < 4; ++nf) {
        float e0 = EXP2(s[mb][nf][0]);
        float e1 = EXP2(s[mb][nf][1]);
        float e2 = EXP2(s[mb][nf][2]);
        float e3 = EXP2(s[mb][nf][3]);
        lp += (e0 + e1) + (e2 + e3);
        W[nf][0] = cvtpk_bf16(e0, e1);
        W[nf][1] = cvtpk_bf16(e2, e3);
      }
      l_acc[mb] += lp;
#pragma unroll
      for (int ki = 0; ki < 2; ++ki) {
        u32x2 a0  = pl32swap(W[2 * ki][0], W[2 * ki + 1][0]);
        u32x2 t02 = pl16swap(a0.x, a0.y);   // (T0, T2)
        u32x2 a1  = pl32swap(W[2 * ki][1], W[2 * ki + 1][1]);
        u32x2 t13 = pl16swap(a1.x, a1.y);   // (T1, T3)
        union { unsigned u[4]; bf16x8 v; } pu;
        pu.u[0] = t02.x; pu.u[1] = t13.x; pu.u[2] = t02.y; pu.u[3] = t13.y;
        pf[mb][ki] = pu.v;
      }
    }

    // O += P @ V  (kf/vf reuse across 4 mb is the LDS-traffic win)
#pragma unroll
    for (int nb = 0; nb < 8; ++nb)
#pragma unroll
      for (int ki = 0; ki < 2; ++ki) {
        bf16x8 vf = *(const bf16x8*)&VTsl[(nb * 16 + lr) * LDV + ki * 32 + quad * 8];
#pragma unroll
        for (int mb = 0; mb < 4; ++mb) o[mb][nb] = mfma16(pf[mb][ki], vf, o[mb][nb]);
      }
  }

  // Row-sums live at q-row = lr; reduce the 4 quad-slices, then transpose
  // to q = quad*4+r via shfl for the store.
#pragma unroll
  for (int mb = 0; mb < 4; ++mb) {
    float t = l_acc[mb];
    t += __shfl_xor(t, 16);
    t += __shfl_xor(t, 32);
    l_acc[mb] = t;  // all lanes: L[mb][lr]
  }
#pragma unroll
  for (int mb = 0; mb < 4; ++mb)
#pragma unroll
    for (int r = 0; r < 4; ++r) {
      float Lr = __shfl(l_acc[mb], quad * 4 + r);  // L for q-row quad*4+r
      float inv = 1.0f / Lr;
      int gq = qw + mb * 16 + quad * 4 + r;
#pragma unroll
      for (int nb = 0; nb < 8; ++nb)
        ctx[(size_t)gq * DIM + hoff + nb * 16 + lr] = f2bf(o[mb][nb][r] * inv);
    }
}

extern "C" void kernel_launch(void* const* d_in, const int* in_sizes, int n_in,
                              void* d_out, int out_size, void* d_ws, size_t ws_size,
                              hipStream_t stream) {
  (void)in_sizes; (void)n_in; (void)out_size; (void)ws_size;
  const float* x  = (const float*)d_in[0];
  const float* Wq = (const float*)d_in[1];
  const float* bq = (const float*)d_in[2];
  const float* Wk = (const float*)d_in[3];
  const float* bk = (const float*)d_in[4];
  const float* Wv = (const float*)d_in[5];
  const float* bv = (const float*)d_in[6];
  const float* Wo = (const float*)d_in[7];
  const float* bo = (const float*)d_in[8];

  const size_t NE = (size_t)N_TOK * DIM;  // 8.4M
  unsigned short* xb  = (unsigned short*)d_ws;      // also reused as ctx later
  unsigned short* Wqb = xb + NE;
  unsigned short* Wkb = Wqb + NW;
  unsigned short* Wvb = Wkb + NW;
  unsigned short* Wob = Wvb + NW;
  unsigned short* Qb  = Wob + NW;
  unsigned short* Kb  = Qb + NE;
  unsigned short* Vtb = Kb + NE;   // total ~100.7 MB

  cvt_bf16<<<4096, 256, 0, stream>>>(x,  xb,  (int)NE);
  cvt_bf16<<<2048, 256, 0, stream>>>(Wq, Wqb, NW);
  cvt_bf16<<<2048, 256, 0, stream>>>(Wk, Wkb, NW);
  cvt_bf16<<<2048, 256, 0, stream>>>(Wv, Wvb, NW);
  cvt_bf16<<<2048, 256, 0, stream>>>(Wo, Wob, NW);

  // flat 256-block grids; XCD chunking + decomp inside the kernels (T1)
  const float qscale = 1.4426950408889634f * 0.08838834764831845f;

  gemm_bf16<0><<<256, 512, 0, stream>>>(xb, Wqb, bq, Qb, qscale);
  gemm_bf16<0><<<256, 512, 0, stream>>>(xb, Wkb, bk, Kb, 1.0f);
  gemm_bf16<2><<<256, 512, 0, stream>>>(xb, Wvb, bv, Vtb, 1.0f);

  unsigned short* ctxb = xb;  // x dead after V projection; reuse
  flash_attn<<<256, 256, 0, stream>>>(Qb, Kb, Vtb, ctxb);

  gemm_bf16<1><<<256, 512, 0, stream>>>(ctxb, Wob, bo, (float*)d_out, 1.0f);
}

// Round 12
// 432.996 us; speedup vs baseline: 1.4401x; 1.0471x over previous
//
#include <hip/hip_runtime.h>
#include <stdint.h>

#define N_TOK 4096
#define DIM   2048
#define NH    16
#define HD    128
#define NW    (DIM * DIM)

using bf16x8 = __attribute__((ext_vector_type(8))) short;
using bf16x4 = __attribute__((ext_vector_type(4))) short;
using f32x4  = __attribute__((ext_vector_type(4))) float;
using u32x2  = __attribute__((ext_vector_type(2))) unsigned int;

#if __has_builtin(__builtin_amdgcn_exp2f)
#define EXP2(x) __builtin_amdgcn_exp2f(x)
#else
#define EXP2(x) exp2f(x)
#endif

__device__ inline unsigned short f2bf(float f) {
  union { float f; unsigned u; } v; v.f = f;
  unsigned r = v.u + 0x7FFFu + ((v.u >> 16) & 1u);
  return (unsigned short)(r >> 16);
}
__device__ inline float bf2f(unsigned short u) {
  union { unsigned u; float f; } v; v.u = ((unsigned)u) << 16; return v.f;
}
__device__ inline f32x4 mfma16(bf16x8 a, bf16x8 b, f32x4 c) {
  return __builtin_amdgcn_mfma_f32_16x16x32_bf16(a, b, c, 0, 0, 0);
}
// async global->LDS, 16B per lane; LDS dest = wave-uniform base + lane*16
__device__ inline void gll16(const unsigned short* g, unsigned short* l) {
  __builtin_amdgcn_global_load_lds(
      (const __attribute__((address_space(1))) void*)g,
      (__attribute__((address_space(3))) void*)l, 16, 0, 0);
}
// raw barrier with compiler-only memory fences (no waitcnt emitted)
__device__ inline void wgbar() {
  asm volatile("" ::: "memory");
  __builtin_amdgcn_s_barrier();
  asm volatile("" ::: "memory");
}

// pack two f32 -> one u32 of 2x bf16 (RNE). No builtin on gfx950 (guide T12).
__device__ inline unsigned cvtpk_bf16(float lo, float hi) {
  unsigned r;
  asm("v_cvt_pk_bf16_f32 %0, %1, %2" : "=v"(r) : "v"(lo), "v"(hi));
  return r;
}

// permlane swaps (gfx950). ret.x = {A.lo16/32-groups..}, see call sites.
__device__ inline u32x2 pl32swap(unsigned a, unsigned b) {
#if __has_builtin(__builtin_amdgcn_permlane32_swap)
  return __builtin_amdgcn_permlane32_swap(a, b, false, false);
#else
  int lane = threadIdx.x & 63;
  unsigned as = (unsigned)__shfl_xor((int)a, 32);
  unsigned bs = (unsigned)__shfl_xor((int)b, 32);
  u32x2 r;
  r.x = (lane & 32) ? bs : a;   // {A.lo32, B.lo32}
  r.y = (lane & 32) ? b : as;   // {A.hi32, B.hi32}
  return r;
#endif
}
__device__ inline u32x2 pl16swap(unsigned a, unsigned b) {
#if __has_builtin(__builtin_amdgcn_permlane16_swap)
  return __builtin_amdgcn_permlane16_swap(a, b, false, false);
#else
  int lane = threadIdx.x & 63;
  unsigned as = (unsigned)__shfl_xor((int)a, 16);
  unsigned bs = (unsigned)__shfl_xor((int)b, 16);
  u32x2 r;
  r.x = (lane & 16) ? bs : a;   // {A.g0, B.g0, A.g2, B.g2} (16-lane groups)
  r.y = (lane & 16) ? b : as;   // {A.g1, B.g1, A.g3, B.g3}
  return r;
#endif
}

// fp32 -> bf16 convert, 8 elems/thread
__global__ __launch_bounds__(256)
void cvt_bf16(const float* __restrict__ src, unsigned short* __restrict__ dst, int n) {
  int i = blockIdx.x * 256 + threadIdx.x;
  if (i * 8 >= n) return;
  const float4* s = (const float4*)src + (size_t)i * 2;
  float4 a = s[0], b = s[1];
  bf16x8 o;
  o[0] = (short)f2bf(a.x); o[1] = (short)f2bf(a.y);
  o[2] = (short)f2bf(a.z); o[3] = (short)f2bf(a.w);
  o[4] = (short)f2bf(b.x); o[5] = (short)f2bf(b.y);
  o[6] = (short)f2bf(b.z); o[7] = (short)f2bf(b.w);
  *(bf16x8*)(dst + (size_t)i * 8) = o;
}

// C[4096,2048] = A[4096,2048] @ B[2048,2048]^T (+bias)*scale; all-bf16 inputs.
// R12: BM 256->128 at 2-deep LDS -> 2 INDEPENDENT blocks/CU (grid 512).
// Barrier series closed non-monotone: 8/Ktile=505us, 4=436 (opt), 2=453 --
// per-block schedule is optimized; the missing lever is CROSS-BLOCK overlap
// (m114): at 1 block/CU all 8 waves stall at the same barrier; with 2 blocks
// /CU, block B computes through block A's barrier. Per-wave structure is
// byte-identical to R8 (64x64 out, 2 phases x 16 MFMA, 4 barriers/K-tile).
// 2-deep forces vmcnt(0)/K-tile, but all 8 staging loads issue at ph0
// (cover ~300+ cyc) and are mostly L2 hits (~200 cyc) thanks to T1 swizzle
// (unlike R5's 900-cyc HBM misses -> that's why 2-deep is viable now).
// T1 for 512 blocks: nb=(bid&7)*64+(bid>>3), m-major -> each XCD = 4 m-rows
// x 16 n-blocks, shared A = 2 MB (L2-fits). T2 swizzle via pre-swizzled
// GLOBAL source col (rule 21) + XOR'd ds_read slot.
// Hazards: stage(t+1) writes buf^1, disjoint from buf reads; per-wave
// vmcnt(0) at ph1 + barrier jointly drain every wave's loads before swap.
// OUT_MODE: 0 = bf16 row-major, 1 = fp32 row-major, 2 = bf16 transposed (Vt)
template<int OUT_MODE>
__global__ __launch_bounds__(256, 2)
void gemm_bf16(const unsigned short* __restrict__ A, const unsigned short* __restrict__ B,
               const float* __restrict__ bias, void* __restrict__ out_, float scale) {
  constexpr int BM = 128, BN = 128, BK = 64;
  constexpr int NKT = DIM / BK;              // 32
  __shared__ unsigned short Asl[2][BM * BK]; // 2 x 16 KB
  __shared__ unsigned short Bsl[2][BN * BK]; // 2 x 16 KB  (total 64 KB)

  const int tid  = threadIdx.x;
  const int lane = tid & 63;
  const int w    = tid >> 6;
  const int wm = w >> 1, wn = w & 1;         // 2M x 2N
  const int lr = lane & 15, quad = lane >> 4;

  // T1 chunked XCD swizzle: contiguous 64-block chunk per XCD, m-major.
  const int bid = blockIdx.x;                // 0..511
  const int nb  = (bid & 7) * 64 + (bid >> 3);
  const int m0  = (nb >> 4) * BM;            // 32 m-blocks
  const int n0  = (nb & 15) * BN;            // 16 n-blocks

  const f32x4 vzero = {0.f, 0.f, 0.f, 0.f};
  f32x4 acc[4][4];
#pragma unroll
  for (int i = 0; i < 4; ++i)
#pragma unroll
    for (int j = 0; j < 4; ++j) acc[i][j] = vzero;

  // staging: A 4 chunks/thread, B 4 chunks/thread (16B each), 1024 chunks ea.
  // LDS write linear at ch*16B; global source col pre-swizzled (m173).
  size_t asrc[4]; int aldst[4];
  size_t bsrc[4]; int bldst[4];
#pragma unroll
  for (int i = 0; i < 4; ++i) {
    int ch = tid + i * 256;                  // 0..1023
    int row = ch >> 3, cc = ch & 7;          // 128 rows x 8 chunks
    int gcc = cc ^ (row & 7);
    asrc[i]  = (size_t)(m0 + row) * DIM + gcc * 8;
    aldst[i] = ch * 8;
    bsrc[i]  = (size_t)(n0 + row) * DIM + gcc * 8;
    bldst[i] = ch * 8;
  }
  auto stage_all = [&](int buf, int k0) {    // 8 gll16: whole tile
#pragma unroll
    for (int i = 0; i < 4; ++i) gll16(&A[asrc[i] + k0], &Asl[buf][aldst[i]]);
#pragma unroll
    for (int i = 0; i < 4; ++i) gll16(&B[bsrc[i] + k0], &Bsl[buf][bldst[i]]);
  };

  auto lda = [&](int buf, int ks, bf16x8* af) {
#pragma unroll
    for (int mb = 0; mb < 4; ++mb) {
      int row  = wm * 64 + mb * 16 + lr;
      int slot = (ks * 4 + quad) ^ (row & 7);
      af[mb] = *(const bf16x8*)&Asl[buf][row * 64 + slot * 8];
    }
  };
  auto ldb = [&](int buf, int ks, bf16x8* bfv) {
#pragma unroll
    for (int nb2 = 0; nb2 < 4; ++nb2) {
      int row  = wn * 64 + nb2 * 16 + lr;
      int slot = (ks * 4 + quad) ^ (row & 7);
      bfv[nb2] = *(const bf16x8*)&Bsl[buf][row * 64 + slot * 8];
    }
  };
  auto mm = [&](bf16x8* af, bf16x8* bfv) {   // 16 MFMA
    __builtin_amdgcn_s_setprio(1);
#pragma unroll
    for (int mb = 0; mb < 4; ++mb)
#pragma unroll
      for (int nb2 = 0; nb2 < 4; ++nb2)
        acc[mb][nb2] = mfma16(af[mb], bfv[nb2], acc[mb][nb2]);
    __builtin_amdgcn_s_setprio(0);
  };

  // ---- prologue: stage tile 0, drain, barrier ----
  stage_all(0, 0);
  asm volatile("s_waitcnt vmcnt(0)" ::: "memory");
  wgbar();

  // ---- main loop: R8 phase shape (4 barriers/K-tile), 2-deep pipeline ----
  for (int t = 0; t < NKT - 1; ++t) {
    const int buf = t & 1, sk = (t + 1) * BK;
    bf16x8 af[4], bfv[4];
    // phase 0 (k-slice 0): issue ALL of tile t+1's 8 loads here (max cover)
    lda(buf, 0, af); ldb(buf, 0, bfv);
    stage_all(buf ^ 1, sk);
    wgbar();
    mm(af, bfv);
    wgbar();
    // phase 1 (k-slice 1): drain tile t+1 (covered by ph0 barrier + MFMAs)
    lda(buf, 1, af); ldb(buf, 1, bfv);
    asm volatile("s_waitcnt vmcnt(0)" ::: "memory");
    wgbar();
    mm(af, bfv);
    wgbar();
  }
  // ---- final tile: pure compute, no staging/barriers ----
  {
    const int buf = (NKT - 1) & 1;
    bf16x8 af[4], bfv[4];
    lda(buf, 0, af); ldb(buf, 0, bfv);
    mm(af, bfv);
    lda(buf, 1, af); ldb(buf, 1, bfv);
    mm(af, bfv);
  }

  // ---- C write ----
#pragma unroll
  for (int mb = 0; mb < 4; ++mb)
#pragma unroll
    for (int nb2 = 0; nb2 < 4; ++nb2) {
      int gn = n0 + wn * 64 + nb2 * 16 + lr;
      int gm_base = m0 + wm * 64 + mb * 16 + quad * 4;
      float bs = bias[gn];
      if constexpr (OUT_MODE == 2) {
        bf16x4 pk;
#pragma unroll
        for (int r = 0; r < 4; ++r) pk[r] = (short)f2bf((acc[mb][nb2][r] + bs) * scale);
        *(bf16x4*)&((unsigned short*)out_)[(size_t)gn * N_TOK + gm_base] = pk;
      } else {
#pragma unroll
        for (int r = 0; r < 4; ++r) {
          float v = (acc[mb][nb2][r] + bs) * scale;
          if constexpr (OUT_MODE == 1)
            ((float*)out_)[(size_t)(gm_base + r) * DIM + gn] = v;
          else
            ((unsigned short*)out_)[(size_t)(gm_base + r) * DIM + gn] = f2bf(v);
        }
      }
    }
}

// Flash attention, no-max softmax (scores bounded; exp2 domain folded into Q).
// R8 structure EXACTLY (measured best, 162.5-162.8 us): KVBLK=64, mb=4 (64
// q-rows/wave), grid 256 = 1 block/CU. Frozen: R10's KVB=128 spilled; R2/R4
// stagger failed both occupancy regimes; R8 proved not memory-bound (FETCH
// 139 -> 24.7 MB at unchanged dur).
// Head-chunked XCD swizzle: XCD x owns heads {2x,2x+1}; each XCD's 32 blocks
// share 2 heads' K+V = 4 MB = its L2.
// Swapped QK^T (mfma(K,Q)) -> softmax fully in registers (cvt_pk + permlane).
__global__ __launch_bounds__(256, 1)
void flash_attn(const unsigned short* __restrict__ Q,
                const unsigned short* __restrict__ K,
                const unsigned short* __restrict__ Vt,
                unsigned short* __restrict__ ctx) {
  constexpr int LDK = 136;  // K tile row stride (128+8)
  constexpr int LDV = 72;   // Vt tile row stride (64+8)
  constexpr int NT  = N_TOK / 64;
  __shared__ unsigned short Ksl[64 * LDK];
  __shared__ unsigned short VTsl[128 * LDV];

  const int tid  = threadIdx.x;
  const int lane = tid & 63, w = tid >> 6;
  const int lr = lane & 15, quad = lane >> 4;

  // head-chunked XCD swizzle (bijective: bid = qb*16 + b1*8 + x)
  const int bid  = blockIdx.x;                   // 0..255
  const int head = (bid & 7) * 2 + ((bid >> 3) & 1);
  const int qblk = bid >> 4;
  const int hoff = head * HD;
  const int q0   = qblk * 256;
  const int qw   = q0 + w * 64;

  // Q fragments; L2E/sqrt(128) already folded in at projection.
  // Layout [free=lr (q-row)][k=c*32+quad*8] = B-operand of swapped mfma(K,Q).
  bf16x8 qf[4][4];
#pragma unroll
  for (int mb = 0; mb < 4; ++mb)
#pragma unroll
    for (int c = 0; c < 4; ++c)
      qf[mb][c] = *(const bf16x8*)&Q[(size_t)(qw + mb * 16 + lr) * DIM + hoff + c * 32 + quad * 8];

  const f32x4 vzero = {0.f, 0.f, 0.f, 0.f};
  f32x4 o[4][8];
  float l_acc[4] = {0.f, 0.f, 0.f, 0.f};  // row-sum for q-row = lr (per mb)
#pragma unroll
  for (int mb = 0; mb < 4; ++mb)
#pragma unroll
    for (int nb = 0; nb < 8; ++nb) o[mb][nb] = vzero;

  bf16x8 kreg[4], vreg[4];
  auto load_tile = [&](int kt) {
    int kbase = kt * 64;
#pragma unroll
    for (int i = 0; i < 4; ++i) {
      int ch = tid + i * 256;
      kreg[i] = *(const bf16x8*)&K[(size_t)(kbase + (ch >> 4)) * DIM + hoff + (ch & 15) * 8];
      vreg[i] = *(const bf16x8*)&Vt[(size_t)(hoff + (ch >> 3)) * N_TOK + kbase + (ch & 7) * 8];
    }
  };
  load_tile(0);

  for (int kt = 0; kt < NT; ++kt) {
    __syncthreads();  // previous tile's LDS reads complete
#pragma unroll
    for (int i = 0; i < 4; ++i) {
      int ch = tid + i * 256;
      *(bf16x8*)&Ksl[(ch >> 4) * LDK + (ch & 15) * 8] = kreg[i];
      *(bf16x8*)&VTsl[(ch >> 3) * LDV + (ch & 7) * 8] = vreg[i];
    }
    __syncthreads();
    if (kt + 1 < NT) load_tile(kt + 1);  // global->reg prefetch under compute

    // S^T = K @ Q^T : lane holds S[q = mb*16+lr][key = nf*16 + quad*4 + r]
    f32x4 s[4][4];
#pragma unroll
    for (int mb = 0; mb < 4; ++mb)
#pragma unroll
      for (int nf = 0; nf < 4; ++nf) s[mb][nf] = vzero;
#pragma unroll
    for (int nf = 0; nf < 4; ++nf)
#pragma unroll
      for (int c = 0; c < 4; ++c) {
        bf16x8 kf = *(const bf16x8*)&Ksl[(nf * 16 + lr) * LDK + c * 32 + quad * 8];
#pragma unroll
        for (int mb = 0; mb < 4; ++mb) s[mb][nf] = mfma16(kf, qf[mb][c], s[mb][nf]);
      }

    // In-register softmax + redistribution into PV A-fragments.
    // Target word t of pf[mb][ki] (lane quad q) = keys ki*32 + q*8 + {2t,2t+1}
    //   = source lane quad (q&1)*2 + (t>>1), W[2ki + (q>>1)][t&1].
    bf16x8 pf[4][2];
#pragma unroll
    for (int mb = 0; mb < 4; ++mb) {
      unsigned W[4][2];
      float lp = 0.f;
#pragma unroll
      for (int nf = 0; nf < 4; ++nf) {
        float e0 = EXP2(s[mb][nf][0]);
        float e1 = EXP2(s[mb][nf][1]);
        float e2 = EXP2(s[mb][nf][2]);
        float e3 = EXP2(s[mb][nf][3]);
        lp += (e0 + e1) + (e2 + e3);
        W[nf][0] = cvtpk_bf16(e0, e1);
        W[nf][1] = cvtpk_bf16(e2, e3);
      }
      l_acc[mb] += lp;
#pragma unroll
      for (int ki = 0; ki < 2; ++ki) {
        u32x2 a0  = pl32swap(W[2 * ki][0], W[2 * ki + 1][0]);
        u32x2 t02 = pl16swap(a0.x, a0.y);   // (T0, T2)
        u32x2 a1  = pl32swap(W[2 * ki][1], W[2 * ki + 1][1]);
        u32x2 t13 = pl16swap(a1.x, a1.y);   // (T1, T3)
        union { unsigned u[4]; bf16x8 v; } pu;
        pu.u[0] = t02.x; pu.u[1] = t13.x; pu.u[2] = t02.y; pu.u[3] = t13.y;
        pf[mb][ki] = pu.v;
      }
    }

    // O += P @ V  (kf/vf reuse across 4 mb is the LDS-traffic win)
#pragma unroll
    for (int nb = 0; nb < 8; ++nb)
#pragma unroll
      for (int ki = 0; ki < 2; ++ki) {
        bf16x8 vf = *(const bf16x8*)&VTsl[(nb * 16 + lr) * LDV + ki * 32 + quad * 8];
#pragma unroll
        for (int mb = 0; mb < 4; ++mb) o[mb][nb] = mfma16(pf[mb][ki], vf, o[mb][nb]);
      }
  }

  // Row-sums live at q-row = lr; reduce the 4 quad-slices, then transpose
  // to q = quad*4+r via shfl for the store.
#pragma unroll
  for (int mb = 0; mb < 4; ++mb) {
    float t = l_acc[mb];
    t += __shfl_xor(t, 16);
    t += __shfl_xor(t, 32);
    l_acc[mb] = t;  // all lanes: L[mb][lr]
  }
#pragma unroll
  for (int mb = 0; mb < 4; ++mb)
#pragma unroll
    for (int r = 0; r < 4; ++r) {
      float Lr = __shfl(l_acc[mb], quad * 4 + r);  // L for q-row quad*4+r
      float inv = 1.0f / Lr;
      int gq = qw + mb * 16 + quad * 4 + r;
#pragma unroll
      for (int nb = 0; nb < 8; ++nb)
        ctx[(size_t)gq * DIM + hoff + nb * 16 + lr] = f2bf(o[mb][nb][r] * inv);
    }
}

extern "C" void kernel_launch(void* const* d_in, const int* in_sizes, int n_in,
                              void* d_out, int out_size, void* d_ws, size_t ws_size,
                              hipStream_t stream) {
  (void)in_sizes; (void)n_in; (void)out_size; (void)ws_size;
  const float* x  = (const float*)d_in[0];
  const float* Wq = (const float*)d_in[1];
  const float* bq = (const float*)d_in[2];
  const float* Wk = (const float*)d_in[3];
  const float* bk = (const float*)d_in[4];
  const float* Wv = (const float*)d_in[5];
  const float* bv = (const float*)d_in[6];
  const float* Wo = (const float*)d_in[7];
  const float* bo = (const float*)d_in[8];

  const size_t NE = (size_t)N_TOK * DIM;  // 8.4M
  unsigned short* xb  = (unsigned short*)d_ws;      // also reused as ctx later
  unsigned short* Wqb = xb + NE;
  unsigned short* Wkb = Wqb + NW;
  unsigned short* Wvb = Wkb + NW;
  unsigned short* Wob = Wvb + NW;
  unsigned short* Qb  = Wob + NW;
  unsigned short* Kb  = Qb + NE;
  unsigned short* Vtb = Kb + NE;   // total ~100.7 MB

  cvt_bf16<<<4096, 256, 0, stream>>>(x,  xb,  (int)NE);
  cvt_bf16<<<2048, 256, 0, stream>>>(Wq, Wqb, NW);
  cvt_bf16<<<2048, 256, 0, stream>>>(Wk, Wkb, NW);
  cvt_bf16<<<2048, 256, 0, stream>>>(Wv, Wvb, NW);
  cvt_bf16<<<2048, 256, 0, stream>>>(Wo, Wob, NW);

  // flat grids; XCD chunking + decomp inside the kernels (T1)
  const float qscale = 1.4426950408889634f * 0.08838834764831845f;

  gemm_bf16<0><<<512, 256, 0, stream>>>(xb, Wqb, bq, Qb, qscale);
  gemm_bf16<0><<<512, 256, 0, stream>>>(xb, Wkb, bk, Kb, 1.0f);
  gemm_bf16<2><<<512, 256, 0, stream>>>(xb, Wvb, bv, Vtb, 1.0f);

  unsigned short* ctxb = xb;  // x dead after V projection; reuse
  flash_attn<<<256, 256, 0, stream>>>(Qb, Kb, Vtb, ctxb);

  gemm_bf16<1><<<512, 256, 0, stream>>>(ctxb, Wob, bo, (float*)d_out, 1.0f);
}